// Round 4
// baseline (855.810 us; speedup 1.0000x reference)
//
#include <hip/hip_runtime.h>
#include <hip/hip_bf16.h>
#include <math.h>

#define SEQ 2048
#define DKH 64
#define NH 16
#define NEGV -10000.0f
#define LIST_CAP 160

typedef __attribute__((ext_vector_type(8))) short short8;
typedef __attribute__((ext_vector_type(4))) float f32x4;

__device__ __forceinline__ unsigned int f2k(float f) {
  unsigned int u = __float_as_uint(f);
  return (u & 0x80000000u) ? ~u : (u | 0x80000000u);
}
__device__ __forceinline__ float k2f(unsigned int k) {
  unsigned int u = (k & 0x80000000u) ? (k & 0x7FFFFFFFu) : ~k;
  return __uint_as_float(u);
}
__device__ __forceinline__ int lanecnt_lt(unsigned long long m) {
  return __builtin_amdgcn_mbcnt_hi((unsigned int)(m >> 32),
         __builtin_amdgcn_mbcnt_lo((unsigned int)m, 0));
}
__device__ __forceinline__ void split_hl(float x, unsigned short* h, unsigned short* l) {
  unsigned int u = __float_as_uint(x);
  *h = (unsigned short)(u >> 16);
  float hf = __uint_as_float(u & 0xffff0000u);
  *l = (unsigned short)(__float_as_uint(x - hf) >> 16);
}
__device__ __forceinline__ void glds16(const unsigned short* g, unsigned short* l) {
  __builtin_amdgcn_global_load_lds(
      (const __attribute__((address_space(1))) unsigned int*)g,
      (__attribute__((address_space(3))) unsigned int*)l, 16, 0, 0);
}
// LDS-only barrier: waits own LDS ops, does NOT drain vmcnt (global K loads
// stay in flight across it — they only target this wave's VGPRs).
__device__ __forceinline__ void lds_barrier() {
  asm volatile("s_waitcnt lgkmcnt(0)" ::: "memory");
  __builtin_amdgcn_s_barrier();
  asm volatile("" ::: "memory");
}

// ---------------------------------------------------------------------------
// fp32 -> [hi(1024) | lo(1024)] bf16 planes, row-major M x 2048 ushort.
// ---------------------------------------------------------------------------
__global__ __launch_bounds__(256)
void conv_xhl(const float* __restrict__ X, unsigned short* __restrict__ O)
{
  int idx = blockIdx.x * 256 + threadIdx.x;   // one thread per 4 elements
  int m = idx >> 8;
  int c = (idx & 255) * 4;
  float4 v = *(const float4*)(X + (size_t)m * 1024 + c);
  float xs[4] = {v.x, v.y, v.z, v.w};
  ushort4 h, l;
  unsigned short hh[4], ll[4];
#pragma unroll
  for (int q = 0; q < 4; q++) split_hl(xs[q], &hh[q], &ll[q]);
  h.x=hh[0]; h.y=hh[1]; h.z=hh[2]; h.w=hh[3];
  l.x=ll[0]; l.y=ll[1]; l.z=ll[2]; l.w=ll[3];
  *(ushort4*)(O + (size_t)m * 2048 + c) = h;
  *(ushort4*)(O + (size_t)m * 2048 + 1024 + c) = l;
}

// Same for weights (1024 x 1024 fp32 -> 1024 x 2048 hl).
__global__ __launch_bounds__(256)
void conv_whl(const float* __restrict__ W, unsigned short* __restrict__ O)
{
  int idx = blockIdx.x * 256 + threadIdx.x;
  int n = idx >> 8;
  int c = (idx & 255) * 4;
  float4 v = *(const float4*)(W + (size_t)n * 1024 + c);
  float xs[4] = {v.x, v.y, v.z, v.w};
  ushort4 h, l;
  unsigned short hh[4], ll[4];
#pragma unroll
  for (int q = 0; q < 4; q++) split_hl(xs[q], &hh[q], &ll[q]);
  h.x=hh[0]; h.y=hh[1]; h.z=hh[2]; h.w=hh[3];
  l.x=ll[0]; l.y=ll[1]; l.z=ll[2]; l.w=ll[3];
  *(ushort4*)(O + (size_t)n * 2048 + c) = h;
  *(ushort4*)(O + (size_t)n * 2048 + 1024 + c) = l;
}

// ---------------------------------------------------------------------------
// Split-bf16 MFMA GEMM: C[m,n] = sum_c X[m,c]*W[n,c] + bias[n] computed as
// Xhi*Whi + Xhi*Wlo + Xlo*Whi via a single ext-K loop (Kext=3072).
// A: M x 2048 hl, B: N x 2048 hl. Tile 128(M) x 64(N), BK=128 (24 K-steps,
// half the barrier drains of BK=64 — grid=512 pins 2 blocks/CU so the m132
// occupancy cliff doesn't apply). XCD-swizzled block ids (512%8==0,
// bijective) group 16 same-mb tiles per XCD L2.
// Epilogue modes: 0 fp32 [m][n]; 1 bhsd hl (q,k); 2 bhsd fp32 (v).
// ---------------------------------------------------------------------------
__global__ __launch_bounds__(256)
void gemm_mfma(const unsigned short* __restrict__ A,
               const unsigned short* __restrict__ Bw,
               const float* __restrict__ bias,
               float* __restrict__ outF,
               unsigned short* __restrict__ outHL,
               float* __restrict__ outBH,
               int mode)
{
  __shared__ unsigned short As[128 * 128];   // 32 KB
  __shared__ unsigned short Bs[64 * 128];    // 16 KB
  const int t = threadIdx.x, lane = t & 63, w = t >> 6;
  const int bid = blockIdx.x;
  const int swz = (bid & 7) * 64 + (bid >> 3);   // XCD-aware, bijective
  const int nb = swz & 15, mb = swz >> 4;
  const int m0 = mb * 128, n0 = nb * 64;
  const int am = lane & 15, aq = lane >> 4;
  const int wr = w >> 1, wc = w & 1;
  const int srow = lane >> 4;          // 4 rows per wave-instruction
  const int scol = (lane & 15) * 8;    // 128-col rows

  f32x4 acc[4][2];
#pragma unroll
  for (int mt = 0; mt < 4; mt++)
#pragma unroll
    for (int nt = 0; nt < 2; nt++) acc[mt][nt] = (f32x4){0.f, 0.f, 0.f, 0.f};

  for (int kx = 0; kx < 3072; kx += 128) {
    const int acol = (kx < 1024) ? kx : kx - 1024;   // hi, hi, lo
    const int bcol = (kx < 2048) ? kx : kx - 2048;   // hi, lo, hi
    __syncthreads();
#pragma unroll
    for (int ch = 0; ch < 8; ch++) {                 // A: 128 rows, 8 chunks/wave
      int row = w * 32 + ch * 4 + srow;
      glds16(A + (size_t)(m0 + row) * 2048 + acol + scol,
             &As[(w * 32 + ch * 4) * 128 + lane * 8]);
    }
#pragma unroll
    for (int ch = 0; ch < 4; ch++) {                 // B: 64 rows, 4 chunks/wave
      int row = w * 16 + ch * 4 + srow;
      glds16(Bw + (size_t)(n0 + row) * 2048 + bcol + scol,
             &Bs[(w * 16 + ch * 4) * 128 + lane * 8]);
    }
    __syncthreads();

#pragma unroll
    for (int kk = 0; kk < 4; kk++) {
      short8 af[4], bf[2];
#pragma unroll
      for (int mt = 0; mt < 4; mt++)
        af[mt] = *(const short8*)&As[(wr * 64 + mt * 16 + am) * 128 + kk * 32 + aq * 8];
#pragma unroll
      for (int nt = 0; nt < 2; nt++)
        bf[nt] = *(const short8*)&Bs[(wc * 32 + nt * 16 + am) * 128 + kk * 32 + aq * 8];
#pragma unroll
      for (int mt = 0; mt < 4; mt++)
#pragma unroll
        for (int nt = 0; nt < 2; nt++)
          acc[mt][nt] = __builtin_amdgcn_mfma_f32_16x16x32_bf16(af[mt], bf[nt], acc[mt][nt], 0, 0, 0);
    }
  }

#pragma unroll
  for (int mt = 0; mt < 4; mt++)
#pragma unroll
    for (int nt = 0; nt < 2; nt++)
#pragma unroll
      for (int reg = 0; reg < 4; reg++) {
        const int gm = m0 + wr * 64 + mt * 16 + aq * 4 + reg;
        const int gn = n0 + wc * 32 + nt * 16 + am;
        float val = acc[mt][nt][reg] + bias[gn];
        if (mode == 0) {
          outF[(size_t)gm * 1024 + gn] = val;
        } else {
          const int bb = gm >> 11, s = gm & 2047, h2 = gn >> 6, d = gn & 63;
          const size_t row = ((size_t)(bb * NH + h2)) * SEQ + s;
          if (mode == 2) {
            outBH[row * DKH + d] = val;
          } else {
            unsigned short h, l;
            split_hl(val, &h, &l);
            outHL[row * 128 + d] = h;
            outHL[row * 128 + 64 + d] = l;
          }
        }
      }
}

// ---------------------------------------------------------------------------
// Attention: split-bf16 MFMA QK^T + exact causal top-64 + sparse PV.
// 16-ROW BLOCKS (1024 thr, 16 waves): the 16x16 MFMA A-fragment now carries
// 16 REAL query rows, so the full MFMA output is kept — phase-1 MFMA, K-loads
// and stores HALVE vs the 8-row blocks (which discarded rows 8..15).
// Scores staged in FOUR 512-key slices, padded [16][516] (store 2-way=free).
// Raw lgkm-only barriers keep global loads in flight across slice stages.
// Phase 2 unchanged: one row/wave, keys[32] register-resident (compile-time
// indices — NO tight waves-per-EU cap: (512,8) spilled keys to scratch,
// +210 MB HBM; launch_bounds(1024,4) leaves the allocator free).
// Selection: statistical probe seeds exact bisection (~2-3 count passes).
// PV double-buffered.
// ---------------------------------------------------------------------------
struct AttnSmem {
  float scores[16][516];                // 33 KB, one staged slice (padded)
  float2 pl[16][LIST_CAP + 8];          // 21 KB packed (p, j) kept list + pad
  float cand[16][64];                   // 4 KB
};

// absorb one staged slice (8 chunks) into keys[U0..U0+7]; U0 must be a
// literal so every keys[] index is compile-time (else -> scratch).
#define LOAD_CHUNKS(U0)                                                      \
  {                                                                          \
    _Pragma("unroll")                                                        \
    for (int ul = 0; ul < 8; ul++) {                                         \
      const int u = (U0) + ul;                                               \
      float vm = NEGV;                                                       \
      if ((u << 6) <= i) {                                                   \
        const int j = (u << 6) + lane;                                       \
        float v = sm.scores[r][(ul << 6) + lane];                            \
        bool ok = (j <= i);                                                  \
        vm = ok ? v : NEGV;                                                  \
        float va = ok ? v : 0.0f;                                            \
        vmax = fmaxf(vmax, vm);                                              \
        s1 += va;                                                            \
        s2 = fmaf(va, va, s2);                                               \
      }                                                                      \
      keys[u] = f2k(vm);                                                     \
    }                                                                        \
  }

__global__ __launch_bounds__(1024, 4)
void attn_topk(const unsigned short* __restrict__ qhl, const unsigned short* __restrict__ khl,
               const float* __restrict__ vp, unsigned short* __restrict__ aohl)
{
  __shared__ AttnSmem sm;
  const int t    = threadIdx.x;
  const int lane = t & 63;
  const int w    = t >> 6;            // 0..15
  const int bh   = blockIdx.x >> 7;
  const int rb   = 127 - (blockIdx.x & 127);   // heavy blocks dispatch first
  const int i0   = rb * 16;
  const unsigned short* qb = qhl + (size_t)bh * SEQ * 128;
  const unsigned short* kb = khl + (size_t)bh * SEQ * 128;
  const float* vbase = vp + (size_t)bh * SEQ * DKH;

  // ---- phase 1/absorb interleaved per 512-key slice ----
  const int am   = lane & 15;
  const int aq   = lane >> 4;
  const int dofs = aq * 8;
  const int r = w;
  const int i = i0 + w;

  short8 a_hi[2], a_lo[2];
#pragma unroll
  for (int c = 0; c < 2; c++) {
    size_t off = (size_t)(i0 + am) * 128 + c * 32 + dofs;  // 16 real rows
    a_hi[c] = *(const short8*)(qb + off);
    a_lo[c] = *(const short8*)(qb + off + 64);
  }

  const int T = (i0 >> 4) + 1;

  // compute tiles [s*32, min(T, s*32+32)) of QK^T into sm.scores (slice-local
  // cols). 16 waves cover a slice in 2 statically-unrolled reps; per tile the
  // full 16-reg fragment preload (round-1 ILP; the per-c reload regressed).
  auto phase1_stage = [&](int s) {
    const int tlo = s << 5;
    const int thi = (T < tlo + 32) ? T : (tlo + 32);
    const int cb0 = s << 9;
#pragma unroll
    for (int rep = 0; rep < 2; rep++) {
      const int tt = tlo + w + rep * 16;
      if (tt < thi) {
        short8 b_hi[2], b_lo[2];
#pragma unroll
        for (int c = 0; c < 2; c++) {
          size_t off = (size_t)(tt * 16 + am) * 128 + c * 32 + dofs;
          b_hi[c] = *(const short8*)(kb + off);
          b_lo[c] = *(const short8*)(kb + off + 64);
        }
        f32x4 C = {0.0f, 0.0f, 0.0f, 0.0f};
#pragma unroll
        for (int c = 0; c < 2; c++) {
          C = __builtin_amdgcn_mfma_f32_16x16x32_bf16(a_hi[c], b_hi[c], C, 0, 0, 0);
          C = __builtin_amdgcn_mfma_f32_16x16x32_bf16(a_lo[c], b_hi[c], C, 0, 0, 0);
          C = __builtin_amdgcn_mfma_f32_16x16x32_bf16(a_hi[c], b_lo[c], C, 0, 0, 0);
        }
        const int j = tt * 16 + am;
        const int jc = j - cb0;
#pragma unroll
        for (int reg = 0; reg < 4; reg++) {
          const int rr = aq * 4 + reg;       // all 16 rows kept
          sm.scores[rr][jc] = (j <= i0 + rr) ? C[reg] * 0.125f : NEGV;
        }
      }
    }
  };

  unsigned int keys[32];
  float vmax = NEGV, s1 = 0.0f, s2 = 0.0f;

  // slice s is needed iff i0 >= s*512 (block-uniform -> barrier-safe)
  phase1_stage(0);
  lds_barrier();
  LOAD_CHUNKS(0)
  if (i0 >= 512) {
    lds_barrier();                     // all waves done reading slice 0
    phase1_stage(1);
    lds_barrier();
    LOAD_CHUNKS(8)
    if (i0 >= 1024) {
      lds_barrier();
      phase1_stage(2);
      lds_barrier();
      LOAD_CHUNKS(16)
      if (i0 >= 1536) {
        lds_barrier();
        phase1_stage(3);
        lds_barrier();
        LOAD_CHUNKS(24)
      }
    }
  } else {
#pragma unroll
    for (int u = 8; u < 32; u++) keys[u] = f2k(NEGV);
  }
  if (i0 >= 512 && i0 < 1024) {
#pragma unroll
    for (int u = 16; u < 32; u++) keys[u] = f2k(NEGV);
  }
  if (i0 >= 1024 && i0 < 1536) {
#pragma unroll
    for (int u = 24; u < 32; u++) keys[u] = f2k(NEGV);
  }

  // ---- selection: stats reduction + probe-seeded exact bisection ----
#pragma unroll
  for (int off = 32; off; off >>= 1) {
    vmax = fmaxf(vmax, __shfl_xor(vmax, off));
    s1 += __shfl_xor(s1, off);
    s2 += __shfl_xor(s2, off);
  }

  auto countge = [&](unsigned int km) -> int {
    int cnt = 0;
#pragma unroll
    for (int u = 0; u < 32; u++)
      if ((u << 6) <= i)
        cnt += __popcll(__ballot(keys[u] >= km));
    return cnt;
  };

  float vk;
  if (i + 1 <= 64) {
    vk = NEGV;                         // <=64 valid: keep all
  } else {
    const float n1  = (float)(i + 1);
    const float mu  = s1 / n1;
    const float sig = sqrtf(fmaxf(s2 / n1 - mu * mu, 0.0f));
    // inverse-normal probe targeting count ~128 (Hastings approx)
    const float qf = fminf(0.45f, 128.0f / n1);
    const float tq = sqrtf(-2.0f * __logf(qf));
    const float zq = tq - (2.30753f + 0.27061f * tq) /
                          (1.0f + tq * (0.99229f + 0.04481f * tq));
    unsigned int ka, kb2;
    int ca, cb;
    {
      const float t1 = mu + zq * sig;
      const unsigned int kt1 = f2k(t1);
      const int c1 = countge(kt1);
      if (c1 >= 64) { ka = kt1; ca = c1; kb2 = f2k(vmax) + 1u; cb = 0; }
      else {
        const float t2 = mu + (zq - 0.85f) * sig;
        const unsigned int kt2 = f2k(t2);
        const int c2 = countge(kt2);
        if (c2 >= 64) { ka = kt2; ca = c2; kb2 = kt1; cb = c1; }
        else { ka = f2k(-5000.0f); ca = i + 1; kb2 = kt2; cb = c2; }
      }
    }
    int guard = 0;
    while (kb2 - ka > 1u && (ca - cb) > 56 && guard < 64) {
      guard++;
      float fm = 0.5f * (k2f(ka) + k2f(kb2));
      unsigned int km = f2k(fm);
      if (km <= ka || km >= kb2) km = ka + ((kb2 - ka) >> 1);
      const int cnt = countge(km);
      if (cnt >= 64) { ka = km; ca = cnt; } else { kb2 = km; cb = cnt; }
    }
    if (kb2 - ka == 1u || (ca - cb) > 64) {
      vk = k2f(ka);                    // interval collapsed (dups) -> exact
    } else {
      int cbase = 0;
#pragma unroll
      for (int u = 0; u < 32; u++) {
        if ((u << 6) <= i) {
          unsigned int kx = keys[u];
          bool in = (kx >= ka && kx < kb2);
          unsigned long long mask = __ballot(in);
          if (in) sm.cand[w][cbase + lanecnt_lt(mask)] = k2f(kx);
          cbase += __popcll(mask);
        }
      }
      const int nc = cbase;            // <= 64 on this path
      float cv = (lane < nc) ? sm.cand[w][lane] : -3.4e38f;
      for (int ks = 2; ks <= 64; ks <<= 1) {
        for (int j2 = ks >> 1; j2 > 0; j2 >>= 1) {
          float other = __shfl_xor(cv, j2);
          bool up    = ((lane & ks) == 0);
          bool lower = ((lane & j2) == 0);
          float mn = fminf(cv, other), mx = fmaxf(cv, other);
          cv = (up == lower) ? mn : mx;
        }
      }
      int need = 64 - cb;
      vk = __shfl(cv, 64 - need);
    }
  }

  // softmax + packed (p, j) kept list
  float z = 0.0f;
  int base = 0;
#pragma unroll
  for (int u = 0; u < 32; u++) {
    if ((u << 6) <= i) {
      const int j = (u << 6) + lane;
      float sv = k2f(keys[u]);
      float p = (sv >= vk) ? __expf(sv - vmax) : 0.0f;  // NEG entries -> exactly 0
      z += p;
      unsigned long long mask = __ballot(p > 0.0f);
      if (p > 0.0f) {
        int pos = base + lanecnt_lt(mask);
        if (pos < LIST_CAP) {
          float2 e; e.x = p; e.y = __uint_as_float((unsigned int)j);
          sm.pl[r][pos] = e;
        }
      }
      base += __popcll(mask);
    }
  }
#pragma unroll
  for (int off = 32; off; off >>= 1) z += __shfl_xor(z, off);
  const float rz = 1.0f / z;

  // sparse PV: double-buffered batches of 8 (list prefetch + 8 gathers in flight)
  float acc = 0.0f;
  if (base <= LIST_CAP) {
    if (lane < 8) {                    // zero-pad so batches are branch-free
      float2 e; e.x = 0.0f; e.y = __uint_as_float(0u);
      sm.pl[r][base + lane] = e;
    }
    const int nb2 = (base + 7) >> 3;
    float2 cur[8], nxt[8];
#pragma unroll
    for (int s = 0; s < 8; s++) cur[s] = sm.pl[r][s];
    for (int b = 0; b < nb2; b++) {
      float vv[8];
#pragma unroll
      for (int s = 0; s < 8; s++) {
        const unsigned int jx = __float_as_uint(cur[s].y);
        vv[s] = vbase[(unsigned int)((jx << 6) | (unsigned int)lane)];
      }
      const int nbase = (b + 1) * 8;
#pragma unroll
      for (int s = 0; s < 8; s++) {
        int idx = nbase + s; if (idx > LIST_CAP + 7) idx = 0;
        nxt[s] = sm.pl[r][idx];
      }
#pragma unroll
      for (int s = 0; s < 8; s++) acc = fmaf(cur[s].x, vv[s], acc);
#pragma unroll
      for (int s = 0; s < 8; s++) cur[s] = nxt[s];
    }
  } else {                             // ties pathology: dense from registers
#pragma unroll
    for (int u = 0; u < 32; u++) {
      if ((u << 6) <= i) {
        float svu = k2f(keys[u]);      // static index: keys stay in VGPRs
        for (int l2 = 0; l2 < 64; l2++) {
          const int jx = (u << 6) + l2;
          if (jx > i) break;
          float sv = __shfl(svu, l2);
          float p = (sv >= vk) ? __expf(sv - vmax) : 0.0f;
          acc = fmaf(p, vbase[(unsigned int)((jx << 6) | (unsigned int)lane)], acc);
        }
      }
    }
  }

  // epilogue: write ao as hl planes (row-major M x 2048) for the final GEMM
  const int bb = bh >> 4, hh = bh & 15;
  float val = acc * rz;
  unsigned short h, l;
  split_hl(val, &h, &l);
  const size_t arow = (size_t)(bb * SEQ + i) * 2048;
  aohl[arow + hh * 64 + lane] = h;
  aohl[arow + 1024 + hh * 64 + lane] = l;
}

// ---------------------------------------------------------------------------
extern "C" void kernel_launch(void* const* d_in, const int* in_sizes, int n_in,
                              void* d_out, int out_size, void* d_ws, size_t ws_size,
                              hipStream_t stream)
{
  const float* query = (const float*)d_in[0];
  const float* key   = (const float*)d_in[1];
  const float* value = (const float*)d_in[2];
  const float* Wq    = (const float*)d_in[3];
  const float* bq    = (const float*)d_in[4];
  const float* Wk    = (const float*)d_in[5];
  const float* bk    = (const float*)d_in[6];
  const float* Wv    = (const float*)d_in[7];
  const float* bv    = (const float*)d_in[8];
  const float* Wo    = (const float*)d_in[9];
  const float* bo    = (const float*)d_in[10];

  // ws (54.5 MB): xhl(16) | whl(4) | qhl(16) | khl(16). V fp32 lives in d_out
  // (scratch until the final GEMM overwrites it).
  unsigned short* xhl = (unsigned short*)d_ws;            // 4096 x 2048
  unsigned short* whl = xhl + (size_t)4096 * 2048;        // 1024 x 2048
  unsigned short* qhl = whl + (size_t)1024 * 2048;        // 65536 x 128 (bhsd hl)
  unsigned short* khl = qhl + (size_t)65536 * 128;
  float* vpf = (float*)d_out;                             // 65536 x 64 fp32 (bhsd)

  hipLaunchKernelGGL(conv_xhl, dim3(4096), dim3(256), 0, stream, query, xhl);
  hipLaunchKernelGGL(conv_whl, dim3(1024), dim3(256), 0, stream, Wq, whl);
  hipLaunchKernelGGL(gemm_mfma, dim3(512), dim3(256), 0, stream, xhl, whl, bq,
                     (float*)nullptr, qhl, (float*)nullptr, 1);
  hipLaunchKernelGGL(conv_xhl, dim3(4096), dim3(256), 0, stream, key, xhl);
  hipLaunchKernelGGL(conv_whl, dim3(1024), dim3(256), 0, stream, Wk, whl);
  hipLaunchKernelGGL(gemm_mfma, dim3(512), dim3(256), 0, stream, xhl, whl, bk,
                     (float*)nullptr, khl, (float*)nullptr, 1);
  hipLaunchKernelGGL(conv_xhl, dim3(4096), dim3(256), 0, stream, value, xhl);
  hipLaunchKernelGGL(conv_whl, dim3(1024), dim3(256), 0, stream, Wv, whl);
  hipLaunchKernelGGL(gemm_mfma, dim3(512), dim3(256), 0, stream, xhl, whl, bv,
                     (float*)nullptr, (unsigned short*)nullptr, vpf, 2);
  hipLaunchKernelGGL(attn_topk, dim3(4096), dim3(1024), 0, stream, qhl, khl, vpf, xhl);
  hipLaunchKernelGGL(conv_whl, dim3(1024), dim3(256), 0, stream, Wo, whl);
  hipLaunchKernelGGL(gemm_mfma, dim3(512), dim3(256), 0, stream, xhl, whl, bo,
                     (float*)d_out, (unsigned short*)nullptr, (float*)nullptr, 0);
}

// Round 5
// 743.985 us; speedup vs baseline: 1.1503x; 1.1503x over previous
//
#include <hip/hip_runtime.h>
#include <hip/hip_bf16.h>
#include <math.h>

#define SEQ 2048
#define DKH 64
#define NH 16
#define NEGV -10000.0f
#define LIST_CAP 160

typedef __attribute__((ext_vector_type(8))) short short8;
typedef __attribute__((ext_vector_type(4))) float f32x4;

__device__ __forceinline__ unsigned int f2k(float f) {
  unsigned int u = __float_as_uint(f);
  return (u & 0x80000000u) ? ~u : (u | 0x80000000u);
}
__device__ __forceinline__ float k2f(unsigned int k) {
  unsigned int u = (k & 0x80000000u) ? (k & 0x7FFFFFFFu) : ~k;
  return __uint_as_float(u);
}
__device__ __forceinline__ int lanecnt_lt(unsigned long long m) {
  return __builtin_amdgcn_mbcnt_hi((unsigned int)(m >> 32),
         __builtin_amdgcn_mbcnt_lo((unsigned int)m, 0));
}
__device__ __forceinline__ void split_hl(float x, unsigned short* h, unsigned short* l) {
  unsigned int u = __float_as_uint(x);
  *h = (unsigned short)(u >> 16);
  float hf = __uint_as_float(u & 0xffff0000u);
  *l = (unsigned short)(__float_as_uint(x - hf) >> 16);
}
__device__ __forceinline__ void glds16(const unsigned short* g, unsigned short* l) {
  __builtin_amdgcn_global_load_lds(
      (const __attribute__((address_space(1))) unsigned int*)g,
      (__attribute__((address_space(3))) unsigned int*)l, 16, 0, 0);
}
// LDS-only barrier: waits own LDS ops, does NOT drain vmcnt (global K loads
// stay in flight across it — they only target this wave's VGPRs).
__device__ __forceinline__ void lds_barrier() {
  asm volatile("s_waitcnt lgkmcnt(0)" ::: "memory");
  __builtin_amdgcn_s_barrier();
  asm volatile("" ::: "memory");
}

// ---------------------------------------------------------------------------
// fp32 -> [hi(1024) | lo(1024)] bf16 planes, row-major M x 2048 ushort.
// ---------------------------------------------------------------------------
__global__ __launch_bounds__(256)
void conv_xhl(const float* __restrict__ X, unsigned short* __restrict__ O)
{
  int idx = blockIdx.x * 256 + threadIdx.x;   // one thread per 4 elements
  int m = idx >> 8;
  int c = (idx & 255) * 4;
  float4 v = *(const float4*)(X + (size_t)m * 1024 + c);
  float xs[4] = {v.x, v.y, v.z, v.w};
  ushort4 h, l;
  unsigned short hh[4], ll[4];
#pragma unroll
  for (int q = 0; q < 4; q++) split_hl(xs[q], &hh[q], &ll[q]);
  h.x=hh[0]; h.y=hh[1]; h.z=hh[2]; h.w=hh[3];
  l.x=ll[0]; l.y=ll[1]; l.z=ll[2]; l.w=ll[3];
  *(ushort4*)(O + (size_t)m * 2048 + c) = h;
  *(ushort4*)(O + (size_t)m * 2048 + 1024 + c) = l;
}

// Same for weights (1024 x 1024 fp32 -> 1024 x 2048 hl).
__global__ __launch_bounds__(256)
void conv_whl(const float* __restrict__ W, unsigned short* __restrict__ O)
{
  int idx = blockIdx.x * 256 + threadIdx.x;
  int n = idx >> 8;
  int c = (idx & 255) * 4;
  float4 v = *(const float4*)(W + (size_t)n * 1024 + c);
  float xs[4] = {v.x, v.y, v.z, v.w};
  ushort4 h, l;
  unsigned short hh[4], ll[4];
#pragma unroll
  for (int q = 0; q < 4; q++) split_hl(xs[q], &hh[q], &ll[q]);
  h.x=hh[0]; h.y=hh[1]; h.z=hh[2]; h.w=hh[3];
  l.x=ll[0]; l.y=ll[1]; l.z=ll[2]; l.w=ll[3];
  *(ushort4*)(O + (size_t)n * 2048 + c) = h;
  *(ushort4*)(O + (size_t)n * 2048 + 1024 + c) = l;
}

// ---------------------------------------------------------------------------
// Split-bf16 MFMA GEMM: C[m,n] = sum_c X[m,c]*W[n,c] + bias[n] computed as
// Xhi*Whi + Xhi*Wlo + Xlo*Whi via a single ext-K loop (Kext=3072).
// A: M x 2048 hl, B: N x 2048 hl. Tile 128(M) x 64(N), BK=64, 256 thr.
// PROVEN ~300 us chain (rounds 0/1/3). BK=128 + XCD swizzle regressed +114 us
// (round 4) — reverted, do not re-bundle untested GEMM changes.
// Epilogue modes: 0 fp32 [m][n]; 1 bhsd hl (q,k); 2 bhsd fp32 (v).
// ---------------------------------------------------------------------------
__global__ __launch_bounds__(256)
void gemm_mfma(const unsigned short* __restrict__ A,
               const unsigned short* __restrict__ Bw,
               const float* __restrict__ bias,
               float* __restrict__ outF,
               unsigned short* __restrict__ outHL,
               float* __restrict__ outBH,
               int mode)
{
  __shared__ unsigned short As[128 * 64];
  __shared__ unsigned short Bs[64 * 64];
  const int t = threadIdx.x, lane = t & 63, w = t >> 6;
  const int nb = blockIdx.x & 15, mb = blockIdx.x >> 4;
  const int m0 = mb * 128, n0 = nb * 64;
  const int am = lane & 15, aq = lane >> 4;
  const int wr = w >> 1, wc = w & 1;
  const int srow = lane >> 3;
  const int scol = (lane & 7) * 8;

  f32x4 acc[4][2];
#pragma unroll
  for (int mt = 0; mt < 4; mt++)
#pragma unroll
    for (int nt = 0; nt < 2; nt++) acc[mt][nt] = (f32x4){0.f, 0.f, 0.f, 0.f};

  for (int kx = 0; kx < 3072; kx += 64) {
    const int acol = (kx < 1024) ? kx : kx - 1024;   // hi, hi, lo
    const int bcol = (kx < 2048) ? kx : kx - 2048;   // hi, lo, hi
    __syncthreads();
#pragma unroll
    for (int ch = 0; ch < 4; ch++) {                 // A: 128 rows, 4 chunks/wave
      int row = w * 32 + ch * 8 + srow;
      glds16(A + (size_t)(m0 + row) * 2048 + acol + scol,
             &As[(w * 32 + ch * 8) * 64 + lane * 8]);
    }
#pragma unroll
    for (int ch = 0; ch < 2; ch++) {                 // B: 64 rows, 2 chunks/wave
      int row = w * 16 + ch * 8 + srow;
      glds16(Bw + (size_t)(n0 + row) * 2048 + bcol + scol,
             &Bs[(w * 16 + ch * 8) * 64 + lane * 8]);
    }
    __syncthreads();

    short8 af[4][2], bf[2][2];
#pragma unroll
    for (int kk = 0; kk < 2; kk++) {
#pragma unroll
      for (int mt = 0; mt < 4; mt++)
        af[mt][kk] = *(const short8*)&As[(wr * 64 + mt * 16 + am) * 64 + kk * 32 + aq * 8];
#pragma unroll
      for (int nt = 0; nt < 2; nt++)
        bf[nt][kk] = *(const short8*)&Bs[(wc * 32 + nt * 16 + am) * 64 + kk * 32 + aq * 8];
    }
#pragma unroll
    for (int kk = 0; kk < 2; kk++)
#pragma unroll
      for (int mt = 0; mt < 4; mt++)
#pragma unroll
        for (int nt = 0; nt < 2; nt++)
          acc[mt][nt] = __builtin_amdgcn_mfma_f32_16x16x32_bf16(af[mt][kk], bf[nt][kk], acc[mt][nt], 0, 0, 0);
  }

#pragma unroll
  for (int mt = 0; mt < 4; mt++)
#pragma unroll
    for (int nt = 0; nt < 2; nt++)
#pragma unroll
      for (int reg = 0; reg < 4; reg++) {
        const int gm = m0 + wr * 64 + mt * 16 + aq * 4 + reg;
        const int gn = n0 + wc * 32 + nt * 16 + am;
        float val = acc[mt][nt][reg] + bias[gn];
        if (mode == 0) {
          outF[(size_t)gm * 1024 + gn] = val;
        } else {
          const int bb = gm >> 11, s = gm & 2047, h2 = gn >> 6, d = gn & 63;
          const size_t row = ((size_t)(bb * NH + h2)) * SEQ + s;
          if (mode == 2) {
            outBH[row * DKH + d] = val;
          } else {
            unsigned short h, l;
            split_hl(val, &h, &l);
            outHL[row * 128 + d] = h;
            outHL[row * 128 + 64 + d] = l;
          }
        }
      }
}

// ---------------------------------------------------------------------------
// Attention: split-bf16 MFMA QK^T + exact causal top-64 + sparse PV.
// Round-1 structure (best measured: 427 us): 512 thr, 8 rows/block, scores
// staged in TWO 1024-key halves (LDS 47.1 KB -> 3 blocks/CU), full 16-reg
// per-tile fragment preload, lgkm-only barriers.
// THIS ROUND'S SINGLE CHANGE: PV is two-deep software-pipelined — two
// independent 8-gather batches (A/B) in flight, refill of one overlapping
// consumption of the other. Round-4 established PV latency (not QK^T, not
// occupancy) as the dominant cost: halving phase-1 MFMA moved dur by ~1%.
// Pad is 32 zero-entries (refills run up to 3 batches past base; unpadded
// reads would gather garbage jx -> OOB). Prologue gathers issue before the
// z-reduce for extra overlap.
// ---------------------------------------------------------------------------
struct AttnSmem {
  float scores[8][1024];                // 32 KB, staged half of the row
  float2 pl[8][LIST_CAP + 32];          // 12 KB packed (p, j) list + 32 pad
  float cand[8][64];                    // 2 KB
};

// absorb one staged half (16 chunks) into keys[U0..U0+15]; U0 literal so
// every keys[] index is compile-time (else -> scratch).
#define LOAD_CHUNKS(U0)                                                      \
  {                                                                          \
    _Pragma("unroll")                                                        \
    for (int ul = 0; ul < 16; ul++) {                                        \
      const int u = (U0) + ul;                                               \
      if ((u << 6) <= i) {                                                   \
        const int j = (u << 6) + lane;                                       \
        float v = sm.scores[r][(ul << 6) + lane];                            \
        bool ok = (j <= i);                                                  \
        float vm = ok ? v : NEGV;                                            \
        float va = ok ? v : 0.0f;                                            \
        vmax = fmaxf(vmax, vm);                                              \
        s1 += va;                                                            \
        s2 = fmaf(va, va, s2);                                               \
        keys[u] = f2k(vm);                                                   \
      }                                                                      \
    }                                                                        \
  }

__global__ __launch_bounds__(512, 6)
void attn_topk(const unsigned short* __restrict__ qhl, const unsigned short* __restrict__ khl,
               const float* __restrict__ vp, unsigned short* __restrict__ aohl)
{
  __shared__ AttnSmem sm;
  const int t    = threadIdx.x;
  const int lane = t & 63;
  const int w    = t >> 6;            // 0..7
  const int bh   = blockIdx.x >> 8;
  const int rb   = 255 - (blockIdx.x & 255);   // heavy blocks dispatch first
  const int i0   = rb * 8;
  const unsigned short* qb = qhl + (size_t)bh * SEQ * 128;
  const unsigned short* kb = khl + (size_t)bh * SEQ * 128;
  const float* vbase = vp + (size_t)bh * SEQ * DKH;

  // ---- phase 1/absorb interleaved per 1024-key half ----
  const int am   = lane & 15;
  const int aq   = lane >> 4;
  const int dofs = aq * 8;
  const int r = w;
  const int i = i0 + w;

  short8 a_hi[2], a_lo[2];
#pragma unroll
  for (int c = 0; c < 2; c++) {
    size_t off = (size_t)(i0 + am) * 128 + c * 32 + dofs;  // rows 8..15 over-read -> next buffer, discarded
    a_hi[c] = *(const short8*)(qb + off);
    a_lo[c] = *(const short8*)(qb + off + 64);
  }

  const int T = (i0 >> 4) + 1;

  // compute tiles [s*64, min(T, s*64+64)) of QK^T into sm.scores (half-local
  // cols). Full 16-reg fragment preload per tile (round-3's per-c reload
  // halved MLP and regressed — keep the preload).
  auto phase1_stage = [&](int s) {
    const int tlo = s << 6;
    const int thi = (T < tlo + 64) ? T : (tlo + 64);
    for (int tt = tlo + w; tt < thi; tt += 8) {
      short8 b_hi[2], b_lo[2];
#pragma unroll
      for (int c = 0; c < 2; c++) {
        size_t off = (size_t)(tt * 16 + am) * 128 + c * 32 + dofs;
        b_hi[c] = *(const short8*)(kb + off);
        b_lo[c] = *(const short8*)(kb + off + 64);
      }
      f32x4 C = {0.0f, 0.0f, 0.0f, 0.0f};
#pragma unroll
      for (int c = 0; c < 2; c++) {
        C = __builtin_amdgcn_mfma_f32_16x16x32_bf16(a_hi[c], b_hi[c], C, 0, 0, 0);
        C = __builtin_amdgcn_mfma_f32_16x16x32_bf16(a_lo[c], b_hi[c], C, 0, 0, 0);
        C = __builtin_amdgcn_mfma_f32_16x16x32_bf16(a_hi[c], b_lo[c], C, 0, 0, 0);
      }
      if (aq < 2) {
        const int j = tt * 16 + am;
        const int jc = j - (s << 10);
#pragma unroll
        for (int reg = 0; reg < 4; reg++) {
          const int rr = aq * 4 + reg;
          sm.scores[rr][jc] = (j <= i0 + rr) ? C[reg] * 0.125f : NEGV;
        }
      }
    }
  };

  unsigned int keys[32];
#pragma unroll
  for (int u = 0; u < 32; u++) keys[u] = f2k(NEGV);
  float vmax = NEGV, s1 = 0.0f, s2 = 0.0f;

  phase1_stage(0);
  lds_barrier();
  LOAD_CHUNKS(0)
  if (i0 >= 1024) {                    // block-uniform: second half exists
    lds_barrier();                     // all waves done reading half 0
    phase1_stage(1);
    lds_barrier();
    LOAD_CHUNKS(16)
  }

  // ---- selection: stats reduction + probe-seeded exact bisection ----
#pragma unroll
  for (int off = 32; off; off >>= 1) {
    vmax = fmaxf(vmax, __shfl_xor(vmax, off));
    s1 += __shfl_xor(s1, off);
    s2 += __shfl_xor(s2, off);
  }

  auto countge = [&](unsigned int km) -> int {
    int cnt = 0;
#pragma unroll
    for (int u = 0; u < 32; u++)
      if ((u << 6) <= i)
        cnt += __popcll(__ballot(keys[u] >= km));
    return cnt;
  };

  float vk;
  if (i + 1 <= 64) {
    vk = NEGV;                         // <=64 valid: keep all
  } else {
    const float n1  = (float)(i + 1);
    const float mu  = s1 / n1;
    const float sig = sqrtf(fmaxf(s2 / n1 - mu * mu, 0.0f));
    // inverse-normal probe targeting count ~128 (Hastings approx)
    const float qf = fminf(0.45f, 128.0f / n1);
    const float tq = sqrtf(-2.0f * __logf(qf));
    const float zq = tq - (2.30753f + 0.27061f * tq) /
                          (1.0f + tq * (0.99229f + 0.04481f * tq));
    unsigned int ka, kb2;
    int ca, cb;
    {
      const float t1 = mu + zq * sig;
      const unsigned int kt1 = f2k(t1);
      const int c1 = countge(kt1);
      if (c1 >= 64) { ka = kt1; ca = c1; kb2 = f2k(vmax) + 1u; cb = 0; }
      else {
        const float t2 = mu + (zq - 0.85f) * sig;
        const unsigned int kt2 = f2k(t2);
        const int c2 = countge(kt2);
        if (c2 >= 64) { ka = kt2; ca = c2; kb2 = kt1; cb = c1; }
        else { ka = f2k(-5000.0f); ca = i + 1; kb2 = kt2; cb = c2; }
      }
    }
    int guard = 0;
    while (kb2 - ka > 1u && (ca - cb) > 56 && guard < 64) {
      guard++;
      float fm = 0.5f * (k2f(ka) + k2f(kb2));
      unsigned int km = f2k(fm);
      if (km <= ka || km >= kb2) km = ka + ((kb2 - ka) >> 1);
      const int cnt = countge(km);
      if (cnt >= 64) { ka = km; ca = cnt; } else { kb2 = km; cb = cnt; }
    }
    if (kb2 - ka == 1u || (ca - cb) > 64) {
      vk = k2f(ka);                    // interval collapsed (dups) -> exact
    } else {
      int cbase = 0;
#pragma unroll
      for (int u = 0; u < 32; u++) {
        if ((u << 6) <= i) {
          unsigned int kx = keys[u];
          bool in = (kx >= ka && kx < kb2);
          unsigned long long mask = __ballot(in);
          if (in) sm.cand[w][cbase + lanecnt_lt(mask)] = k2f(kx);
          cbase += __popcll(mask);
        }
      }
      const int nc = cbase;            // <= 64 on this path
      float cv = (lane < nc) ? sm.cand[w][lane] : -3.4e38f;
      for (int ks = 2; ks <= 64; ks <<= 1) {
        for (int j2 = ks >> 1; j2 > 0; j2 >>= 1) {
          float other = __shfl_xor(cv, j2);
          bool up    = ((lane & ks) == 0);
          bool lower = ((lane & j2) == 0);
          float mn = fminf(cv, other), mx = fmaxf(cv, other);
          cv = (up == lower) ? mn : mx;
        }
      }
      int need = 64 - cb;
      vk = __shfl(cv, 64 - need);
    }
  }

  // softmax + packed (p, j) kept list
  float z = 0.0f;
  int base = 0;
#pragma unroll
  for (int u = 0; u < 32; u++) {
    if ((u << 6) <= i) {
      const int j = (u << 6) + lane;
      float sv = k2f(keys[u]);
      float p = (sv >= vk) ? __expf(sv - vmax) : 0.0f;  // NEG entries -> exactly 0
      z += p;
      unsigned long long mask = __ballot(p > 0.0f);
      if (p > 0.0f) {
        int pos = base + lanecnt_lt(mask);
        if (pos < LIST_CAP) {
          float2 e; e.x = p; e.y = __uint_as_float((unsigned int)j);
          sm.pl[r][pos] = e;
        }
      }
      base += __popcll(mask);
    }
  }

  // ---- sparse PV, two-deep pipelined: prologue issues BEFORE z-reduce ----
  const float* vb2 = vbase + lane;
  float2 curA[8], curB[8];
  float vvA[8], vvB[8];
  const bool sparse = (base <= LIST_CAP);
  if (sparse) {
    if (lane < 32) {                   // 32 zero-pads: refills run 3 batches
      float2 e; e.x = 0.0f; e.y = __uint_as_float(0u);   // past base
      sm.pl[r][base + lane] = e;
    }
#pragma unroll
    for (int s = 0; s < 8; s++) curA[s] = sm.pl[r][s];
#pragma unroll
    for (int s = 0; s < 8; s++) curB[s] = sm.pl[r][8 + s];
#pragma unroll
    for (int s = 0; s < 8; s++)
      vvA[s] = vb2[(size_t)(__float_as_uint(curA[s].y) << 6)];
#pragma unroll
    for (int s = 0; s < 8; s++)
      vvB[s] = vb2[(size_t)(__float_as_uint(curB[s].y) << 6)];
  }

#pragma unroll
  for (int off = 32; off; off >>= 1) z += __shfl_xor(z, off);
  const float rz = 1.0f / z;

  float acc = 0.0f;
  if (sparse) {
    const int nb2 = (base + 7) >> 3;
    for (int b = 0; b < nb2; b += 2) {
      // consume A (batch b), refill A with batch b+2
#pragma unroll
      for (int s = 0; s < 8; s++) acc = fmaf(curA[s].x, vvA[s], acc);
      const int ia = (b + 2) * 8;
#pragma unroll
      for (int s = 0; s < 8; s++) {
        int idx = ia + s; if (idx > LIST_CAP + 31) idx = 0;
        curA[s] = sm.pl[r][idx];
      }
#pragma unroll
      for (int s = 0; s < 8; s++)
        vvA[s] = vb2[(size_t)(__float_as_uint(curA[s].y) << 6)];
      // consume B (batch b+1), refill B with batch b+3
#pragma unroll
      for (int s = 0; s < 8; s++) acc = fmaf(curB[s].x, vvB[s], acc);
      const int ib = (b + 3) * 8;
#pragma unroll
      for (int s = 0; s < 8; s++) {
        int idx = ib + s; if (idx > LIST_CAP + 31) idx = 0;
        curB[s] = sm.pl[r][idx];
      }
#pragma unroll
      for (int s = 0; s < 8; s++)
        vvB[s] = vb2[(size_t)(__float_as_uint(curB[s].y) << 6)];
    }
  } else {                             // ties pathology: dense from registers
#pragma unroll
    for (int u = 0; u < 32; u++) {
      if ((u << 6) <= i) {
        float svu = k2f(keys[u]);      // static index: keys stay in VGPRs
        for (int l2 = 0; l2 < 64; l2++) {
          const int jx = (u << 6) + l2;
          if (jx > i) break;
          float sv = __shfl(svu, l2);
          float p = (sv >= vk) ? __expf(sv - vmax) : 0.0f;
          acc = fmaf(p, vb2[(size_t)((unsigned int)jx << 6)], acc);
        }
      }
    }
  }

  // epilogue: write ao as hl planes (row-major M x 2048) for the final GEMM
  const int bb = bh >> 4, hh = bh & 15;
  float val = acc * rz;
  unsigned short h, l;
  split_hl(val, &h, &l);
  const size_t arow = (size_t)(bb * SEQ + i) * 2048;
  aohl[arow + hh * 64 + lane] = h;
  aohl[arow + 1024 + hh * 64 + lane] = l;
}

// ---------------------------------------------------------------------------
extern "C" void kernel_launch(void* const* d_in, const int* in_sizes, int n_in,
                              void* d_out, int out_size, void* d_ws, size_t ws_size,
                              hipStream_t stream)
{
  const float* query = (const float*)d_in[0];
  const float* key   = (const float*)d_in[1];
  const float* value = (const float*)d_in[2];
  const float* Wq    = (const float*)d_in[3];
  const float* bq    = (const float*)d_in[4];
  const float* Wk    = (const float*)d_in[5];
  const float* bk    = (const float*)d_in[6];
  const float* Wv    = (const float*)d_in[7];
  const float* bv    = (const float*)d_in[8];
  const float* Wo    = (const float*)d_in[9];
  const float* bo    = (const float*)d_in[10];

  // ws (54.5 MB): xhl(16) | whl(4) | qhl(16) | khl(16). V fp32 lives in d_out
  // (scratch until the final GEMM overwrites it).
  unsigned short* xhl = (unsigned short*)d_ws;            // 4096 x 2048
  unsigned short* whl = xhl + (size_t)4096 * 2048;        // 1024 x 2048
  unsigned short* qhl = whl + (size_t)1024 * 2048;        // 65536 x 128 (bhsd hl)
  unsigned short* khl = qhl + (size_t)65536 * 128;
  float* vpf = (float*)d_out;                             // 65536 x 64 fp32 (bhsd)

  hipLaunchKernelGGL(conv_xhl, dim3(4096), dim3(256), 0, stream, query, xhl);
  hipLaunchKernelGGL(conv_whl, dim3(1024), dim3(256), 0, stream, Wq, whl);
  hipLaunchKernelGGL(gemm_mfma, dim3(512), dim3(256), 0, stream, xhl, whl, bq,
                     (float*)nullptr, qhl, (float*)nullptr, 1);
  hipLaunchKernelGGL(conv_xhl, dim3(4096), dim3(256), 0, stream, key, xhl);
  hipLaunchKernelGGL(conv_whl, dim3(1024), dim3(256), 0, stream, Wk, whl);
  hipLaunchKernelGGL(gemm_mfma, dim3(512), dim3(256), 0, stream, xhl, whl, bk,
                     (float*)nullptr, khl, (float*)nullptr, 1);
  hipLaunchKernelGGL(conv_xhl, dim3(4096), dim3(256), 0, stream, value, xhl);
  hipLaunchKernelGGL(conv_whl, dim3(1024), dim3(256), 0, stream, Wv, whl);
  hipLaunchKernelGGL(gemm_mfma, dim3(512), dim3(256), 0, stream, xhl, whl, bv,
                     (float*)nullptr, (unsigned short*)nullptr, vpf, 2);
  hipLaunchKernelGGL(attn_topk, dim3(8192), dim3(512), 0, stream, qhl, khl, vpf, xhl);
  hipLaunchKernelGGL(conv_whl, dim3(1024), dim3(256), 0, stream, Wo, whl);
  hipLaunchKernelGGL(gemm_mfma, dim3(512), dim3(256), 0, stream, xhl, whl, bo,
                     (float*)d_out, (unsigned short*)nullptr, (float*)nullptr, 0);
}

// Round 6
// 726.318 us; speedup vs baseline: 1.1783x; 1.0243x over previous
//
#include <hip/hip_runtime.h>
#include <hip/hip_bf16.h>
#include <math.h>

#define SEQ 2048
#define DKH 64
#define NH 16
#define NEGV -10000.0f
#define LIST_CAP 160

typedef __attribute__((ext_vector_type(8))) short short8;
typedef __attribute__((ext_vector_type(4))) float f32x4;

__device__ __forceinline__ unsigned int f2k(float f) {
  unsigned int u = __float_as_uint(f);
  return (u & 0x80000000u) ? ~u : (u | 0x80000000u);
}
__device__ __forceinline__ float k2f(unsigned int k) {
  unsigned int u = (k & 0x80000000u) ? (k & 0x7FFFFFFFu) : ~k;
  return __uint_as_float(u);
}
__device__ __forceinline__ int lanecnt_lt(unsigned long long m) {
  return __builtin_amdgcn_mbcnt_hi((unsigned int)(m >> 32),
         __builtin_amdgcn_mbcnt_lo((unsigned int)m, 0));
}
__device__ __forceinline__ void split_hl(float x, unsigned short* h, unsigned short* l) {
  unsigned int u = __float_as_uint(x);
  *h = (unsigned short)(u >> 16);
  float hf = __uint_as_float(u & 0xffff0000u);
  *l = (unsigned short)(__float_as_uint(x - hf) >> 16);
}
__device__ __forceinline__ void glds16(const unsigned short* g, unsigned short* l) {
  __builtin_amdgcn_global_load_lds(
      (const __attribute__((address_space(1))) unsigned int*)g,
      (__attribute__((address_space(3))) unsigned int*)l, 16, 0, 0);
}
// LDS-only barrier: waits own LDS ops, does NOT drain vmcnt (global K loads
// stay in flight across it — they only target this wave's VGPRs).
__device__ __forceinline__ void lds_barrier() {
  asm volatile("s_waitcnt lgkmcnt(0)" ::: "memory");
  __builtin_amdgcn_s_barrier();
  asm volatile("" ::: "memory");
}

// ---------------------------------------------------------------------------
// fp32 -> [hi(1024) | lo(1024)] bf16 planes, row-major M x 2048 ushort.
// ---------------------------------------------------------------------------
__global__ __launch_bounds__(256)
void conv_xhl(const float* __restrict__ X, unsigned short* __restrict__ O)
{
  int idx = blockIdx.x * 256 + threadIdx.x;   // one thread per 4 elements
  int m = idx >> 8;
  int c = (idx & 255) * 4;
  float4 v = *(const float4*)(X + (size_t)m * 1024 + c);
  float xs[4] = {v.x, v.y, v.z, v.w};
  ushort4 h, l;
  unsigned short hh[4], ll[4];
#pragma unroll
  for (int q = 0; q < 4; q++) split_hl(xs[q], &hh[q], &ll[q]);
  h.x=hh[0]; h.y=hh[1]; h.z=hh[2]; h.w=hh[3];
  l.x=ll[0]; l.y=ll[1]; l.z=ll[2]; l.w=ll[3];
  *(ushort4*)(O + (size_t)m * 2048 + c) = h;
  *(ushort4*)(O + (size_t)m * 2048 + 1024 + c) = l;
}

// Same for weights (1024 x 1024 fp32 -> 1024 x 2048 hl).
__global__ __launch_bounds__(256)
void conv_whl(const float* __restrict__ W, unsigned short* __restrict__ O)
{
  int idx = blockIdx.x * 256 + threadIdx.x;
  int n = idx >> 8;
  int c = (idx & 255) * 4;
  float4 v = *(const float4*)(W + (size_t)n * 1024 + c);
  float xs[4] = {v.x, v.y, v.z, v.w};
  ushort4 h, l;
  unsigned short hh[4], ll[4];
#pragma unroll
  for (int q = 0; q < 4; q++) split_hl(xs[q], &hh[q], &ll[q]);
  h.x=hh[0]; h.y=hh[1]; h.z=hh[2]; h.w=hh[3];
  l.x=ll[0]; l.y=ll[1]; l.z=ll[2]; l.w=ll[3];
  *(ushort4*)(O + (size_t)n * 2048 + c) = h;
  *(ushort4*)(O + (size_t)n * 2048 + 1024 + c) = l;
}

// ---------------------------------------------------------------------------
// Split-bf16 MFMA GEMM: C[m,n] = sum_c X[m,c]*W[n,c] + bias[n] computed as
// Xhi*Whi + Xhi*Wlo + Xlo*Whi via a single ext-K loop (Kext=3072).
// A: M x 2048 hl, B: N x 2048 hl. Tile 128(M) x 64(N), BK=64, 256 thr.
// PROVEN ~300 us chain (rounds 0/1/3). BK=128 + XCD swizzle regressed +114 us
// (round 4) — reverted, do not re-bundle untested GEMM changes.
// Epilogue modes: 0 fp32 [m][n]; 1 bhsd hl (q,k); 2 bhsd fp32 (v).
// ---------------------------------------------------------------------------
__global__ __launch_bounds__(256)
void gemm_mfma(const unsigned short* __restrict__ A,
               const unsigned short* __restrict__ Bw,
               const float* __restrict__ bias,
               float* __restrict__ outF,
               unsigned short* __restrict__ outHL,
               float* __restrict__ outBH,
               int mode)
{
  __shared__ unsigned short As[128 * 64];
  __shared__ unsigned short Bs[64 * 64];
  const int t = threadIdx.x, lane = t & 63, w = t >> 6;
  const int nb = blockIdx.x & 15, mb = blockIdx.x >> 4;
  const int m0 = mb * 128, n0 = nb * 64;
  const int am = lane & 15, aq = lane >> 4;
  const int wr = w >> 1, wc = w & 1;
  const int srow = lane >> 3;
  const int scol = (lane & 7) * 8;

  f32x4 acc[4][2];
#pragma unroll
  for (int mt = 0; mt < 4; mt++)
#pragma unroll
    for (int nt = 0; nt < 2; nt++) acc[mt][nt] = (f32x4){0.f, 0.f, 0.f, 0.f};

  for (int kx = 0; kx < 3072; kx += 64) {
    const int acol = (kx < 1024) ? kx : kx - 1024;   // hi, hi, lo
    const int bcol = (kx < 2048) ? kx : kx - 2048;   // hi, lo, hi
    __syncthreads();
#pragma unroll
    for (int ch = 0; ch < 4; ch++) {                 // A: 128 rows, 4 chunks/wave
      int row = w * 32 + ch * 8 + srow;
      glds16(A + (size_t)(m0 + row) * 2048 + acol + scol,
             &As[(w * 32 + ch * 8) * 64 + lane * 8]);
    }
#pragma unroll
    for (int ch = 0; ch < 2; ch++) {                 // B: 64 rows, 2 chunks/wave
      int row = w * 16 + ch * 8 + srow;
      glds16(Bw + (size_t)(n0 + row) * 2048 + bcol + scol,
             &Bs[(w * 16 + ch * 8) * 64 + lane * 8]);
    }
    __syncthreads();

    short8 af[4][2], bf[2][2];
#pragma unroll
    for (int kk = 0; kk < 2; kk++) {
#pragma unroll
      for (int mt = 0; mt < 4; mt++)
        af[mt][kk] = *(const short8*)&As[(wr * 64 + mt * 16 + am) * 64 + kk * 32 + aq * 8];
#pragma unroll
      for (int nt = 0; nt < 2; nt++)
        bf[nt][kk] = *(const short8*)&Bs[(wc * 32 + nt * 16 + am) * 64 + kk * 32 + aq * 8];
    }
#pragma unroll
    for (int kk = 0; kk < 2; kk++)
#pragma unroll
      for (int mt = 0; mt < 4; mt++)
#pragma unroll
        for (int nt = 0; nt < 2; nt++)
          acc[mt][nt] = __builtin_amdgcn_mfma_f32_16x16x32_bf16(af[mt][kk], bf[nt][kk], acc[mt][nt], 0, 0, 0);
  }

#pragma unroll
  for (int mt = 0; mt < 4; mt++)
#pragma unroll
    for (int nt = 0; nt < 2; nt++)
#pragma unroll
      for (int reg = 0; reg < 4; reg++) {
        const int gm = m0 + wr * 64 + mt * 16 + aq * 4 + reg;
        const int gn = n0 + wc * 32 + nt * 16 + am;
        float val = acc[mt][nt][reg] + bias[gn];
        if (mode == 0) {
          outF[(size_t)gm * 1024 + gn] = val;
        } else {
          const int bb = gm >> 11, s = gm & 2047, h2 = gn >> 6, d = gn & 63;
          const size_t row = ((size_t)(bb * NH + h2)) * SEQ + s;
          if (mode == 2) {
            outBH[row * DKH + d] = val;
          } else {
            unsigned short h, l;
            split_hl(val, &h, &l);
            outHL[row * 128 + d] = h;
            outHL[row * 128 + 64 + d] = l;
          }
        }
      }
}

// ---------------------------------------------------------------------------
// Attention: split-bf16 MFMA QK^T + exact causal top-64 + sparse PV.
// Round-1 phase 1 (best measured): 512 thr, 8 rows/block, scores staged in
// TWO 1024-key halves (LDS 47.1 KB), full 16-reg per-tile fragment preload,
// lgkm-only barriers.
// PV: two-deep software-pipelined (16 gathers in flight). REGISTER LIVENESS
// RULE (round-5 spill lesson): the pipeline state (curA/curB/vvA/vvB = 48
// regs) must be created STRICTLY INSIDE the sparse arm, where keys[32] are
// dead — hoisting it before the sparse/dense branch makes both live at once
// (~100 regs > the (512,6) cap of ~80) and spills keys to scratch
// (+163 MB HBM writes, round 5). Dense fallback (keys-based) is the else.
// ---------------------------------------------------------------------------
struct AttnSmem {
  float scores[8][1024];                // 32 KB, staged half of the row
  float2 pl[8][LIST_CAP + 32];          // 12 KB packed (p, j) list + 32 pad
  float cand[8][64];                    // 2 KB
};

// absorb one staged half (16 chunks) into keys[U0..U0+15]; U0 literal so
// every keys[] index is compile-time (else -> scratch).
#define LOAD_CHUNKS(U0)                                                      \
  {                                                                          \
    _Pragma("unroll")                                                        \
    for (int ul = 0; ul < 16; ul++) {                                        \
      const int u = (U0) + ul;                                               \
      if ((u << 6) <= i) {                                                   \
        const int j = (u << 6) + lane;                                       \
        float v = sm.scores[r][(ul << 6) + lane];                            \
        bool ok = (j <= i);                                                  \
        float vm = ok ? v : NEGV;                                            \
        float va = ok ? v : 0.0f;                                            \
        vmax = fmaxf(vmax, vm);                                              \
        s1 += va;                                                            \
        s2 = fmaf(va, va, s2);                                               \
        keys[u] = f2k(vm);                                                   \
      }                                                                      \
    }                                                                        \
  }

__global__ __launch_bounds__(512, 6)
void attn_topk(const unsigned short* __restrict__ qhl, const unsigned short* __restrict__ khl,
               const float* __restrict__ vp, unsigned short* __restrict__ aohl)
{
  __shared__ AttnSmem sm;
  const int t    = threadIdx.x;
  const int lane = t & 63;
  const int w    = t >> 6;            // 0..7
  const int bh   = blockIdx.x >> 8;
  const int rb   = 255 - (blockIdx.x & 255);   // heavy blocks dispatch first
  const int i0   = rb * 8;
  const unsigned short* qb = qhl + (size_t)bh * SEQ * 128;
  const unsigned short* kb = khl + (size_t)bh * SEQ * 128;
  const float* vbase = vp + (size_t)bh * SEQ * DKH;

  // ---- phase 1/absorb interleaved per 1024-key half ----
  const int am   = lane & 15;
  const int aq   = lane >> 4;
  const int dofs = aq * 8;
  const int r = w;
  const int i = i0 + w;

  short8 a_hi[2], a_lo[2];
#pragma unroll
  for (int c = 0; c < 2; c++) {
    size_t off = (size_t)(i0 + am) * 128 + c * 32 + dofs;  // rows 8..15 over-read -> next buffer, discarded
    a_hi[c] = *(const short8*)(qb + off);
    a_lo[c] = *(const short8*)(qb + off + 64);
  }

  const int T = (i0 >> 4) + 1;

  // compute tiles [s*64, min(T, s*64+64)) of QK^T into sm.scores (half-local
  // cols). Full 16-reg fragment preload per tile (round-3's per-c reload
  // halved MLP and regressed — keep the preload).
  auto phase1_stage = [&](int s) {
    const int tlo = s << 6;
    const int thi = (T < tlo + 64) ? T : (tlo + 64);
    for (int tt = tlo + w; tt < thi; tt += 8) {
      short8 b_hi[2], b_lo[2];
#pragma unroll
      for (int c = 0; c < 2; c++) {
        size_t off = (size_t)(tt * 16 + am) * 128 + c * 32 + dofs;
        b_hi[c] = *(const short8*)(kb + off);
        b_lo[c] = *(const short8*)(kb + off + 64);
      }
      f32x4 C = {0.0f, 0.0f, 0.0f, 0.0f};
#pragma unroll
      for (int c = 0; c < 2; c++) {
        C = __builtin_amdgcn_mfma_f32_16x16x32_bf16(a_hi[c], b_hi[c], C, 0, 0, 0);
        C = __builtin_amdgcn_mfma_f32_16x16x32_bf16(a_lo[c], b_hi[c], C, 0, 0, 0);
        C = __builtin_amdgcn_mfma_f32_16x16x32_bf16(a_hi[c], b_lo[c], C, 0, 0, 0);
      }
      if (aq < 2) {
        const int j = tt * 16 + am;
        const int jc = j - (s << 10);
#pragma unroll
        for (int reg = 0; reg < 4; reg++) {
          const int rr = aq * 4 + reg;
          sm.scores[rr][jc] = (j <= i0 + rr) ? C[reg] * 0.125f : NEGV;
        }
      }
    }
  };

  unsigned int keys[32];
#pragma unroll
  for (int u = 0; u < 32; u++) keys[u] = f2k(NEGV);
  float vmax = NEGV, s1 = 0.0f, s2 = 0.0f;

  phase1_stage(0);
  lds_barrier();
  LOAD_CHUNKS(0)
  if (i0 >= 1024) {                    // block-uniform: second half exists
    lds_barrier();                     // all waves done reading half 0
    phase1_stage(1);
    lds_barrier();
    LOAD_CHUNKS(16)
  }

  // ---- selection: stats reduction + probe-seeded exact bisection ----
#pragma unroll
  for (int off = 32; off; off >>= 1) {
    vmax = fmaxf(vmax, __shfl_xor(vmax, off));
    s1 += __shfl_xor(s1, off);
    s2 += __shfl_xor(s2, off);
  }

  auto countge = [&](unsigned int km) -> int {
    int cnt = 0;
#pragma unroll
    for (int u = 0; u < 32; u++)
      if ((u << 6) <= i)
        cnt += __popcll(__ballot(keys[u] >= km));
    return cnt;
  };

  float vk;
  if (i + 1 <= 64) {
    vk = NEGV;                         // <=64 valid: keep all
  } else {
    const float n1  = (float)(i + 1);
    const float mu  = s1 / n1;
    const float sig = sqrtf(fmaxf(s2 / n1 - mu * mu, 0.0f));
    // inverse-normal probe targeting count ~128 (Hastings approx)
    const float qf = fminf(0.45f, 128.0f / n1);
    const float tq = sqrtf(-2.0f * __logf(qf));
    const float zq = tq - (2.30753f + 0.27061f * tq) /
                          (1.0f + tq * (0.99229f + 0.04481f * tq));
    unsigned int ka, kb2;
    int ca, cb;
    {
      const float t1 = mu + zq * sig;
      const unsigned int kt1 = f2k(t1);
      const int c1 = countge(kt1);
      if (c1 >= 64) { ka = kt1; ca = c1; kb2 = f2k(vmax) + 1u; cb = 0; }
      else {
        const float t2 = mu + (zq - 0.85f) * sig;
        const unsigned int kt2 = f2k(t2);
        const int c2 = countge(kt2);
        if (c2 >= 64) { ka = kt2; ca = c2; kb2 = kt1; cb = c1; }
        else { ka = f2k(-5000.0f); ca = i + 1; kb2 = kt2; cb = c2; }
      }
    }
    int guard = 0;
    while (kb2 - ka > 1u && (ca - cb) > 56 && guard < 64) {
      guard++;
      float fm = 0.5f * (k2f(ka) + k2f(kb2));
      unsigned int km = f2k(fm);
      if (km <= ka || km >= kb2) km = ka + ((kb2 - ka) >> 1);
      const int cnt = countge(km);
      if (cnt >= 64) { ka = km; ca = cnt; } else { kb2 = km; cb = cnt; }
    }
    if (kb2 - ka == 1u || (ca - cb) > 64) {
      vk = k2f(ka);                    // interval collapsed (dups) -> exact
    } else {
      int cbase = 0;
#pragma unroll
      for (int u = 0; u < 32; u++) {
        if ((u << 6) <= i) {
          unsigned int kx = keys[u];
          bool in = (kx >= ka && kx < kb2);
          unsigned long long mask = __ballot(in);
          if (in) sm.cand[w][cbase + lanecnt_lt(mask)] = k2f(kx);
          cbase += __popcll(mask);
        }
      }
      const int nc = cbase;            // <= 64 on this path
      float cv = (lane < nc) ? sm.cand[w][lane] : -3.4e38f;
      for (int ks = 2; ks <= 64; ks <<= 1) {
        for (int j2 = ks >> 1; j2 > 0; j2 >>= 1) {
          float other = __shfl_xor(cv, j2);
          bool up    = ((lane & ks) == 0);
          bool lower = ((lane & j2) == 0);
          float mn = fminf(cv, other), mx = fmaxf(cv, other);
          cv = (up == lower) ? mn : mx;
        }
      }
      int need = 64 - cb;
      vk = __shfl(cv, 64 - need);
    }
  }

  // softmax + packed (p, j) kept list
  float z = 0.0f;
  int base = 0;
#pragma unroll
  for (int u = 0; u < 32; u++) {
    if ((u << 6) <= i) {
      const int j = (u << 6) + lane;
      float sv = k2f(keys[u]);
      float p = (sv >= vk) ? __expf(sv - vmax) : 0.0f;  // NEG entries -> exactly 0
      z += p;
      unsigned long long mask = __ballot(p > 0.0f);
      if (p > 0.0f) {
        int pos = base + lanecnt_lt(mask);
        if (pos < LIST_CAP) {
          float2 e; e.x = p; e.y = __uint_as_float((unsigned int)j);
          sm.pl[r][pos] = e;
        }
      }
      base += __popcll(mask);
    }
  }
#pragma unroll
  for (int off = 32; off; off >>= 1) z += __shfl_xor(z, off);
  const float rz = 1.0f / z;

  // ---- PV ----
  const float* vb2 = vbase + lane;
  float acc = 0.0f;
  if (base <= LIST_CAP) {
    // sparse: two-deep pipelined batches of 8. keys[] are DEAD on this arm —
    // pipeline state reuses their registers (do not hoist out of this block).
    if (lane < 32) {                   // 32 zero-pads: refills run 3 batches
      float2 e; e.x = 0.0f; e.y = __uint_as_float(0u);   // past base
      sm.pl[r][base + lane] = e;
    }
    float2 curA[8], curB[8];
    float vvA[8], vvB[8];
#pragma unroll
    for (int s = 0; s < 8; s++) curA[s] = sm.pl[r][s];
#pragma unroll
    for (int s = 0; s < 8; s++) curB[s] = sm.pl[r][8 + s];
#pragma unroll
    for (int s = 0; s < 8; s++)
      vvA[s] = vb2[(size_t)(__float_as_uint(curA[s].y) << 6)];
#pragma unroll
    for (int s = 0; s < 8; s++)
      vvB[s] = vb2[(size_t)(__float_as_uint(curB[s].y) << 6)];

    const int nb2 = (base + 7) >> 3;
    for (int b = 0; b < nb2; b += 2) {
      // consume A (batch b), refill A with batch b+2
#pragma unroll
      for (int s = 0; s < 8; s++) acc = fmaf(curA[s].x, vvA[s], acc);
      const int ia = (b + 2) * 8;
#pragma unroll
      for (int s = 0; s < 8; s++) {
        int idx = ia + s; if (idx > LIST_CAP + 31) idx = 0;
        curA[s] = sm.pl[r][idx];
      }
#pragma unroll
      for (int s = 0; s < 8; s++)
        vvA[s] = vb2[(size_t)(__float_as_uint(curA[s].y) << 6)];
      // consume B (batch b+1), refill B with batch b+3
#pragma unroll
      for (int s = 0; s < 8; s++) acc = fmaf(curB[s].x, vvB[s], acc);
      const int ib = (b + 3) * 8;
#pragma unroll
      for (int s = 0; s < 8; s++) {
        int idx = ib + s; if (idx > LIST_CAP + 31) idx = 0;
        curB[s] = sm.pl[r][idx];
      }
#pragma unroll
      for (int s = 0; s < 8; s++)
        vvB[s] = vb2[(size_t)(__float_as_uint(curB[s].y) << 6)];
    }
  } else {                             // ties pathology: dense from registers
#pragma unroll
    for (int u = 0; u < 32; u++) {
      if ((u << 6) <= i) {
        float svu = k2f(keys[u]);      // static index: keys stay in VGPRs
        for (int l2 = 0; l2 < 64; l2++) {
          const int jx = (u << 6) + l2;
          if (jx > i) break;
          float sv = __shfl(svu, l2);
          float p = (sv >= vk) ? __expf(sv - vmax) : 0.0f;
          acc = fmaf(p, vb2[(size_t)((unsigned int)jx << 6)], acc);
        }
      }
    }
  }

  // epilogue: write ao as hl planes (row-major M x 2048) for the final GEMM
  const int bb = bh >> 4, hh = bh & 15;
  float val = acc * rz;
  unsigned short h, l;
  split_hl(val, &h, &l);
  const size_t arow = (size_t)(bb * SEQ + i) * 2048;
  aohl[arow + hh * 64 + lane] = h;
  aohl[arow + 1024 + hh * 64 + lane] = l;
}

// ---------------------------------------------------------------------------
extern "C" void kernel_launch(void* const* d_in, const int* in_sizes, int n_in,
                              void* d_out, int out_size, void* d_ws, size_t ws_size,
                              hipStream_t stream)
{
  const float* query = (const float*)d_in[0];
  const float* key   = (const float*)d_in[1];
  const float* value = (const float*)d_in[2];
  const float* Wq    = (const float*)d_in[3];
  const float* bq    = (const float*)d_in[4];
  const float* Wk    = (const float*)d_in[5];
  const float* bk    = (const float*)d_in[6];
  const float* Wv    = (const float*)d_in[7];
  const float* bv    = (const float*)d_in[8];
  const float* Wo    = (const float*)d_in[9];
  const float* bo    = (const float*)d_in[10];

  // ws (54.5 MB): xhl(16) | whl(4) | qhl(16) | khl(16). V fp32 lives in d_out
  // (scratch until the final GEMM overwrites it).
  unsigned short* xhl = (unsigned short*)d_ws;            // 4096 x 2048
  unsigned short* whl = xhl + (size_t)4096 * 2048;        // 1024 x 2048
  unsigned short* qhl = whl + (size_t)1024 * 2048;        // 65536 x 128 (bhsd hl)
  unsigned short* khl = qhl + (size_t)65536 * 128;
  float* vpf = (float*)d_out;                             // 65536 x 64 fp32 (bhsd)

  hipLaunchKernelGGL(conv_xhl, dim3(4096), dim3(256), 0, stream, query, xhl);
  hipLaunchKernelGGL(conv_whl, dim3(1024), dim3(256), 0, stream, Wq, whl);
  hipLaunchKernelGGL(gemm_mfma, dim3(512), dim3(256), 0, stream, xhl, whl, bq,
                     (float*)nullptr, qhl, (float*)nullptr, 1);
  hipLaunchKernelGGL(conv_xhl, dim3(4096), dim3(256), 0, stream, key, xhl);
  hipLaunchKernelGGL(conv_whl, dim3(1024), dim3(256), 0, stream, Wk, whl);
  hipLaunchKernelGGL(gemm_mfma, dim3(512), dim3(256), 0, stream, xhl, whl, bk,
                     (float*)nullptr, khl, (float*)nullptr, 1);
  hipLaunchKernelGGL(conv_xhl, dim3(4096), dim3(256), 0, stream, value, xhl);
  hipLaunchKernelGGL(conv_whl, dim3(1024), dim3(256), 0, stream, Wv, whl);
  hipLaunchKernelGGL(gemm_mfma, dim3(512), dim3(256), 0, stream, xhl, whl, bv,
                     (float*)nullptr, (unsigned short*)nullptr, vpf, 2);
  hipLaunchKernelGGL(attn_topk, dim3(8192), dim3(512), 0, stream, qhl, khl, vpf, xhl);
  hipLaunchKernelGGL(conv_whl, dim3(1024), dim3(256), 0, stream, Wo, whl);
  hipLaunchKernelGGL(gemm_mfma, dim3(512), dim3(256), 0, stream, xhl, whl, bo,
                     (float*)d_out, (unsigned short*)nullptr, (float*)nullptr, 0);
}

// Round 7
// 657.849 us; speedup vs baseline: 1.3009x; 1.1041x over previous
//
#include <hip/hip_runtime.h>
#include <hip/hip_bf16.h>
#include <math.h>

#define SEQ 2048
#define DKH 64
#define NH 16
#define NEGV -10000.0f
#define LIST_CAP 160
// 0.125 (1/sqrt(dk)) * log2(e): scores stored pre-scaled for exp2 softmax.
// Kept-set and top-k selection are invariant under positive scaling.
#define SSCL 0.18033688f

typedef __attribute__((ext_vector_type(8))) short short8;
typedef __attribute__((ext_vector_type(4))) float f32x4;

__device__ __forceinline__ unsigned int f2k(float f) {
  unsigned int u = __float_as_uint(f);
  return (u & 0x80000000u) ? ~u : (u | 0x80000000u);
}
__device__ __forceinline__ float k2f(unsigned int k) {
  unsigned int u = (k & 0x80000000u) ? (k & 0x7FFFFFFFu) : ~k;
  return __uint_as_float(u);
}
__device__ __forceinline__ int lanecnt_lt(unsigned long long m) {
  return __builtin_amdgcn_mbcnt_hi((unsigned int)(m >> 32),
         __builtin_amdgcn_mbcnt_lo((unsigned int)m, 0));
}
__device__ __forceinline__ void split_hl(float x, unsigned short* h, unsigned short* l) {
  unsigned int u = __float_as_uint(x);
  *h = (unsigned short)(u >> 16);
  float hf = __uint_as_float(u & 0xffff0000u);
  *l = (unsigned short)(__float_as_uint(x - hf) >> 16);
}
__device__ __forceinline__ void glds16(const unsigned short* g, unsigned short* l) {
  __builtin_amdgcn_global_load_lds(
      (const __attribute__((address_space(1))) unsigned int*)g,
      (__attribute__((address_space(3))) unsigned int*)l, 16, 0, 0);
}
// LDS-only barrier: waits own LDS ops, does NOT drain vmcnt.
__device__ __forceinline__ void lds_barrier() {
  asm volatile("s_waitcnt lgkmcnt(0)" ::: "memory");
  __builtin_amdgcn_s_barrier();
  asm volatile("" ::: "memory");
}

// ---------------------------------------------------------------------------
// fp32 -> [hi(1024) | lo(1024)] bf16 planes, row-major M x 2048 ushort.
// ---------------------------------------------------------------------------
__global__ __launch_bounds__(256)
void conv_xhl(const float* __restrict__ X, unsigned short* __restrict__ O)
{
  int idx = blockIdx.x * 256 + threadIdx.x;   // one thread per 4 elements
  int m = idx >> 8;
  int c = (idx & 255) * 4;
  float4 v = *(const float4*)(X + (size_t)m * 1024 + c);
  float xs[4] = {v.x, v.y, v.z, v.w};
  ushort4 h, l;
  unsigned short hh[4], ll[4];
#pragma unroll
  for (int q = 0; q < 4; q++) split_hl(xs[q], &hh[q], &ll[q]);
  h.x=hh[0]; h.y=hh[1]; h.z=hh[2]; h.w=hh[3];
  l.x=ll[0]; l.y=ll[1]; l.z=ll[2]; l.w=ll[3];
  *(ushort4*)(O + (size_t)m * 2048 + c) = h;
  *(ushort4*)(O + (size_t)m * 2048 + 1024 + c) = l;
}

// Same for weights (1024 x 1024 fp32 -> 1024 x 2048 hl).
__global__ __launch_bounds__(256)
void conv_whl(const float* __restrict__ W, unsigned short* __restrict__ O)
{
  int idx = blockIdx.x * 256 + threadIdx.x;
  int n = idx >> 8;
  int c = (idx & 255) * 4;
  float4 v = *(const float4*)(W + (size_t)n * 1024 + c);
  float xs[4] = {v.x, v.y, v.z, v.w};
  ushort4 h, l;
  unsigned short hh[4], ll[4];
#pragma unroll
  for (int q = 0; q < 4; q++) split_hl(xs[q], &hh[q], &ll[q]);
  h.x=hh[0]; h.y=hh[1]; h.z=hh[2]; h.w=hh[3];
  l.x=ll[0]; l.y=ll[1]; l.z=ll[2]; l.w=ll[3];
  *(ushort4*)(O + (size_t)n * 2048 + c) = h;
  *(ushort4*)(O + (size_t)n * 2048 + 1024 + c) = l;
}

// ---------------------------------------------------------------------------
// Split-bf16 MFMA GEMM: C[m,n] = sum_c X[m,c]*W[n,c] + bias[n] computed as
// Xhi*Whi + Xhi*Wlo + Xlo*Whi via a single ext-K loop (Kext=3072).
// A: M x 2048 hl, B: N x 2048 hl. Tile 128(M) x 64(N), BK=64, 256 thr.
// PROVEN ~300 us chain (rounds 0/1/3/5/6). Do not re-bundle untested changes.
// Epilogue modes: 0 fp32 [m][n]; 1 bhsd hl (q,k); 2 bhsd fp32 (v).
// ---------------------------------------------------------------------------
__global__ __launch_bounds__(256)
void gemm_mfma(const unsigned short* __restrict__ A,
               const unsigned short* __restrict__ Bw,
               const float* __restrict__ bias,
               float* __restrict__ outF,
               unsigned short* __restrict__ outHL,
               float* __restrict__ outBH,
               int mode)
{
  __shared__ unsigned short As[128 * 64];
  __shared__ unsigned short Bs[64 * 64];
  const int t = threadIdx.x, lane = t & 63, w = t >> 6;
  const int nb = blockIdx.x & 15, mb = blockIdx.x >> 4;
  const int m0 = mb * 128, n0 = nb * 64;
  const int am = lane & 15, aq = lane >> 4;
  const int wr = w >> 1, wc = w & 1;
  const int srow = lane >> 3;
  const int scol = (lane & 7) * 8;

  f32x4 acc[4][2];
#pragma unroll
  for (int mt = 0; mt < 4; mt++)
#pragma unroll
    for (int nt = 0; nt < 2; nt++) acc[mt][nt] = (f32x4){0.f, 0.f, 0.f, 0.f};

  for (int kx = 0; kx < 3072; kx += 64) {
    const int acol = (kx < 1024) ? kx : kx - 1024;   // hi, hi, lo
    const int bcol = (kx < 2048) ? kx : kx - 2048;   // hi, lo, hi
    __syncthreads();
#pragma unroll
    for (int ch = 0; ch < 4; ch++) {                 // A: 128 rows, 4 chunks/wave
      int row = w * 32 + ch * 8 + srow;
      glds16(A + (size_t)(m0 + row) * 2048 + acol + scol,
             &As[(w * 32 + ch * 8) * 64 + lane * 8]);
    }
#pragma unroll
    for (int ch = 0; ch < 2; ch++) {                 // B: 64 rows, 2 chunks/wave
      int row = w * 16 + ch * 8 + srow;
      glds16(Bw + (size_t)(n0 + row) * 2048 + bcol + scol,
             &Bs[(w * 16 + ch * 8) * 64 + lane * 8]);
    }
    __syncthreads();

    short8 af[4][2], bf[2][2];
#pragma unroll
    for (int kk = 0; kk < 2; kk++) {
#pragma unroll
      for (int mt = 0; mt < 4; mt++)
        af[mt][kk] = *(const short8*)&As[(wr * 64 + mt * 16 + am) * 64 + kk * 32 + aq * 8];
#pragma unroll
      for (int nt = 0; nt < 2; nt++)
        bf[nt][kk] = *(const short8*)&Bs[(wc * 32 + nt * 16 + am) * 64 + kk * 32 + aq * 8];
    }
#pragma unroll
    for (int kk = 0; kk < 2; kk++)
#pragma unroll
      for (int mt = 0; mt < 4; mt++)
#pragma unroll
        for (int nt = 0; nt < 2; nt++)
          acc[mt][nt] = __builtin_amdgcn_mfma_f32_16x16x32_bf16(af[mt][kk], bf[nt][kk], acc[mt][nt], 0, 0, 0);
  }

#pragma unroll
  for (int mt = 0; mt < 4; mt++)
#pragma unroll
    for (int nt = 0; nt < 2; nt++)
#pragma unroll
      for (int reg = 0; reg < 4; reg++) {
        const int gm = m0 + wr * 64 + mt * 16 + aq * 4 + reg;
        const int gn = n0 + wc * 32 + nt * 16 + am;
        float val = acc[mt][nt][reg] + bias[gn];
        if (mode == 0) {
          outF[(size_t)gm * 1024 + gn] = val;
        } else {
          const int bb = gm >> 11, s = gm & 2047, h2 = gn >> 6, d = gn & 63;
          const size_t row = ((size_t)(bb * NH + h2)) * SEQ + s;
          if (mode == 2) {
            outBH[row * DKH + d] = val;
          } else {
            unsigned short h, l;
            split_hl(val, &h, &l);
            outHL[row * 128 + d] = h;
            outHL[row * 128 + 64 + d] = l;
          }
        }
      }
}

// ---------------------------------------------------------------------------
// Attention: split-bf16 MFMA QK^T + exact causal top-64 + sparse PV.
// Round-7 changes (attn-only):
// 1. XCD-AFFINE BLOCK MAP: d&7 selects XCD; each XCD owns 4 heads, so its
//    K panel (2 MB hl) + V (2 MB) fit the per-XCD 4 MB L2. Old mapping
//    round-robined same-head blocks over all 8 XCDs -> 8x K re-fetch
//    (FETCH 139 MB ~= 8 XCD x 32 bh x 524 KB).
// 2. VALU DIET: scores kept as raw floats in regs (sc[32]); f2k/k2f removed
//    from all per-key paths (float compares are monotone; f2k only in the
//    scalar bisection bracket). Phase-1 NEGV-fills the tail to the chunk
//    boundary so LOAD_CHUNKS has no per-lane causal selects. log2e folded
//    into the score scale -> softmax is raw exp2f. PV refill clamp removed
//    (pads provably cover: max touched idx = base+30 < base+32).
// Register liveness rule (round-5 lesson): PV pipeline state lives strictly
// inside the sparse arm where sc[32] are dead.
// ---------------------------------------------------------------------------
struct AttnSmem {
  float scores[8][1024];                // 32 KB, staged half of the row
  float2 pl[8][LIST_CAP + 32];          // 12 KB packed (p, j) list + 32 pad
  float cand[8][64];                    // 2 KB
};

// absorb one staged half (16 chunks) into sc[U0..U0+15]; U0 literal so
// every sc[] index is compile-time (else -> scratch). Causal mask is already
// in LDS (phase-1 writes NEGV beyond each row's bound + tail fill).
#define LOAD_CHUNKS(U0)                                                      \
  {                                                                          \
    _Pragma("unroll")                                                        \
    for (int ul = 0; ul < 16; ul++) {                                        \
      const int u = (U0) + ul;                                               \
      if ((u << 6) <= i) {                                                   \
        float vm = sm.scores[r][(ul << 6) + lane];                           \
        float va = (vm > -5000.0f) ? vm : 0.0f;                              \
        vmax = fmaxf(vmax, vm);                                              \
        s1 += va;                                                            \
        s2 = fmaf(va, va, s2);                                               \
        sc[u] = vm;                                                          \
      }                                                                      \
    }                                                                        \
  }

__global__ __launch_bounds__(512, 6)
void attn_topk(const unsigned short* __restrict__ qhl, const unsigned short* __restrict__ khl,
               const float* __restrict__ vp, unsigned short* __restrict__ aohl)
{
  __shared__ AttnSmem sm;
  const int t    = threadIdx.x;
  const int lane = t & 63;
  const int w    = t >> 6;            // 0..7
  // XCD-affine bijective map: XCD x = d&7 owns heads {4x..4x+3}; heavy rows
  // (large i0) dispatch first within each XCD.
  const int d    = blockIdx.x;
  const int s5   = d >> 3;
  const int bh   = (d & 7) * 4 + (s5 & 3);
  const int rb   = 255 - (s5 >> 2);
  const int i0   = rb * 8;
  const unsigned short* qb = qhl + (size_t)bh * SEQ * 128;
  const unsigned short* kb = khl + (size_t)bh * SEQ * 128;
  const float* vbase = vp + (size_t)bh * SEQ * DKH;

  // ---- phase 1/absorb interleaved per 1024-key half ----
  const int am   = lane & 15;
  const int aq   = lane >> 4;
  const int dofs = aq * 8;
  const int r = w;
  const int i = i0 + w;

  short8 a_hi[2], a_lo[2];
#pragma unroll
  for (int c = 0; c < 2; c++) {
    size_t off = (size_t)(i0 + am) * 128 + c * 32 + dofs;  // rows 8..15 over-read -> next buffer, discarded
    a_hi[c] = *(const short8*)(qb + off);
    a_lo[c] = *(const short8*)(qb + off + 64);
  }

  const int T = (i0 >> 4) + 1;

  // compute tiles [s*64, min(T, s*64+64)) of QK^T into sm.scores (half-local
  // cols), then NEGV-fill the tail up to the 64-chunk boundary so phase-2
  // reads need no per-lane masking. Full 16-reg fragment preload per tile.
  auto phase1_stage = [&](int s) {
    const int tlo = s << 6;
    const int thi = (T < tlo + 64) ? T : (tlo + 64);
    for (int tt = tlo + w; tt < thi; tt += 8) {
      short8 b_hi[2], b_lo[2];
#pragma unroll
      for (int c = 0; c < 2; c++) {
        size_t off = (size_t)(tt * 16 + am) * 128 + c * 32 + dofs;
        b_hi[c] = *(const short8*)(kb + off);
        b_lo[c] = *(const short8*)(kb + off + 64);
      }
      f32x4 C = {0.0f, 0.0f, 0.0f, 0.0f};
#pragma unroll
      for (int c = 0; c < 2; c++) {
        C = __builtin_amdgcn_mfma_f32_16x16x32_bf16(a_hi[c], b_hi[c], C, 0, 0, 0);
        C = __builtin_amdgcn_mfma_f32_16x16x32_bf16(a_lo[c], b_hi[c], C, 0, 0, 0);
        C = __builtin_amdgcn_mfma_f32_16x16x32_bf16(a_hi[c], b_lo[c], C, 0, 0, 0);
      }
      if (aq < 2) {
        const int j = tt * 16 + am;
        const int jc = j - (s << 10);
#pragma unroll
        for (int reg = 0; reg < 4; reg++) {
          const int rr = aq * 4 + reg;
          sm.scores[rr][jc] = (j <= i0 + rr) ? C[reg] * SSCL : NEGV;
        }
      }
    }
    // tail fill: [T*16, next 64-boundary past i0+7), clipped to this stage
    const int fs = T << 4;
    const int fe = (((i0 + 7) >> 6) + 1) << 6;
    const int slo = s << 10, shi = slo + 1024;
    const int lo = fs > slo ? fs : slo;
    const int hi = fe < shi ? fe : shi;
    for (int j = lo + lane; j < hi; j += 64) sm.scores[r][j - slo] = NEGV;
  };

  float sc[32];
#pragma unroll
  for (int u = 0; u < 32; u++) sc[u] = NEGV;
  float vmax = NEGV, s1 = 0.0f, s2 = 0.0f;

  phase1_stage(0);
  lds_barrier();
  LOAD_CHUNKS(0)
  if (i0 >= 1024) {                    // block-uniform: second half exists
    lds_barrier();                     // all waves done reading half 0
    phase1_stage(1);
    lds_barrier();
    LOAD_CHUNKS(16)
  }

  // ---- selection: stats reduction + probe-seeded exact bisection ----
#pragma unroll
  for (int off = 32; off; off >>= 1) {
    vmax = fmaxf(vmax, __shfl_xor(vmax, off));
    s1 += __shfl_xor(s1, off);
    s2 += __shfl_xor(s2, off);
  }

  auto countge = [&](float th) -> int {
    int cnt = 0;
#pragma unroll
    for (int u = 0; u < 32; u++)
      if ((u << 6) <= i)
        cnt += __popcll(__ballot(sc[u] >= th));
    return cnt;
  };

  float vk;
  if (i + 1 <= 64) {
    vk = NEGV;                         // <=64 valid: keep all
  } else {
    const float n1  = (float)(i + 1);
    const float mu  = s1 / n1;
    const float sig = sqrtf(fmaxf(s2 / n1 - mu * mu, 0.0f));
    // inverse-normal probe targeting count ~128 (Hastings approx)
    const float qf = fminf(0.45f, 128.0f / n1);
    const float tq = sqrtf(-2.0f * __logf(qf));
    const float zq = tq - (2.30753f + 0.27061f * tq) /
                          (1.0f + tq * (0.99229f + 0.04481f * tq));
    unsigned int ka, kb2;
    int ca, cb;
    {
      const float t1 = mu + zq * sig;
      const int c1 = countge(t1);
      if (c1 >= 64) { ka = f2k(t1); ca = c1; kb2 = f2k(vmax) + 1u; cb = 0; }
      else {
        const float t2 = mu + (zq - 0.85f) * sig;
        const int c2 = countge(t2);
        if (c2 >= 64) { ka = f2k(t2); ca = c2; kb2 = f2k(t1); cb = c1; }
        else { ka = f2k(-5000.0f); ca = i + 1; kb2 = f2k(t2); cb = c2; }
      }
    }
    int guard = 0;
    while (kb2 - ka > 1u && (ca - cb) > 56 && guard < 64) {
      guard++;
      float fm = 0.5f * (k2f(ka) + k2f(kb2));
      unsigned int km = f2k(fm);
      if (km <= ka || km >= kb2) km = ka + ((kb2 - ka) >> 1);
      const int cnt = countge(k2f(km));
      if (cnt >= 64) { ka = km; ca = cnt; } else { kb2 = km; cb = cnt; }
    }
    if (kb2 - ka == 1u || (ca - cb) > 64) {
      vk = k2f(ka);                    // interval collapsed (dups) -> exact
    } else {
      const float fka = k2f(ka), fkb = k2f(kb2);
      int cbase = 0;
#pragma unroll
      for (int u = 0; u < 32; u++) {
        if ((u << 6) <= i) {
          float kx = sc[u];
          bool in = (kx >= fka && kx < fkb);
          unsigned long long mask = __ballot(in);
          if (in) sm.cand[w][cbase + lanecnt_lt(mask)] = kx;
          cbase += __popcll(mask);
        }
      }
      const int nc = cbase;            // <= 64 on this path
      float cv = (lane < nc) ? sm.cand[w][lane] : -3.4e38f;
      for (int ks = 2; ks <= 64; ks <<= 1) {
        for (int j2 = ks >> 1; j2 > 0; j2 >>= 1) {
          float other = __shfl_xor(cv, j2);
          bool up    = ((lane & ks) == 0);
          bool lower = ((lane & j2) == 0);
          float mn = fminf(cv, other), mx = fmaxf(cv, other);
          cv = (up == lower) ? mn : mx;
        }
      }
      int need = 64 - cb;
      vk = __shfl(cv, 64 - need);
    }
  }

  // softmax + packed (p, j) kept list (scores pre-scaled by log2e -> exp2f)
  float z = 0.0f;
  int base = 0;
#pragma unroll
  for (int u = 0; u < 32; u++) {
    if ((u << 6) <= i) {
      const int j = (u << 6) + lane;
      float sv = sc[u];
      float p = (sv >= vk) ? exp2f(sv - vmax) : 0.0f;  // NEG entries -> exactly 0
      z += p;
      unsigned long long mask = __ballot(p > 0.0f);
      if (p > 0.0f) {
        int pos = base + lanecnt_lt(mask);
        if (pos < LIST_CAP) {
          float2 e; e.x = p; e.y = __uint_as_float((unsigned int)j);
          sm.pl[r][pos] = e;
        }
      }
      base += __popcll(mask);
    }
  }
#pragma unroll
  for (int off = 32; off; off >>= 1) z += __shfl_xor(z, off);
  const float rz = 1.0f / z;

  // ---- PV ----
  const float* vb2 = vbase + lane;
  float acc = 0.0f;
  if (base <= LIST_CAP) {
    // sparse: two-deep pipelined batches of 8. sc[] dead on this arm —
    // pipeline state reuses their registers (do not hoist out of this block).
    if (lane < 32) {                   // 32 zero-pads cover all refills:
      float2 e; e.x = 0.0f; e.y = __uint_as_float(0u);   // max idx = base+30
      sm.pl[r][base + lane] = e;
    }
    float2 curA[8], curB[8];
    float vvA[8], vvB[8];
#pragma unroll
    for (int s = 0; s < 8; s++) curA[s] = sm.pl[r][s];
#pragma unroll
    for (int s = 0; s < 8; s++) curB[s] = sm.pl[r][8 + s];
#pragma unroll
    for (int s = 0; s < 8; s++)
      vvA[s] = vb2[(size_t)(__float_as_uint(curA[s].y) << 6)];
#pragma unroll
    for (int s = 0; s < 8; s++)
      vvB[s] = vb2[(size_t)(__float_as_uint(curB[s].y) << 6)];

    const int nb2 = (base + 7) >> 3;
    for (int b = 0; b < nb2; b += 2) {
      // consume A (batch b), refill A with batch b+2
#pragma unroll
      for (int s = 0; s < 8; s++) acc = fmaf(curA[s].x, vvA[s], acc);
      const int ia = (b + 2) * 8;
#pragma unroll
      for (int s = 0; s < 8; s++) curA[s] = sm.pl[r][ia + s];
#pragma unroll
      for (int s = 0; s < 8; s++)
        vvA[s] = vb2[(size_t)(__float_as_uint(curA[s].y) << 6)];
      // consume B (batch b+1), refill B with batch b+3
#pragma unroll
      for (int s = 0; s < 8; s++) acc = fmaf(curB[s].x, vvB[s], acc);
      const int ib = (b + 3) * 8;
#pragma unroll
      for (int s = 0; s < 8; s++) curB[s] = sm.pl[r][ib + s];
#pragma unroll
      for (int s = 0; s < 8; s++)
        vvB[s] = vb2[(size_t)(__float_as_uint(curB[s].y) << 6)];
    }
  } else {                             // ties pathology: dense from registers
#pragma unroll
    for (int u = 0; u < 32; u++) {
      if ((u << 6) <= i) {
        float svu = sc[u];             // static index: sc stays in VGPRs
        for (int l2 = 0; l2 < 64; l2++) {
          const int jx = (u << 6) + l2;
          if (jx > i) break;
          float sv = __shfl(svu, l2);
          float p = (sv >= vk) ? exp2f(sv - vmax) : 0.0f;
          acc = fmaf(p, vb2[(size_t)((unsigned int)jx << 6)], acc);
        }
      }
    }
  }

  // epilogue: write ao as hl planes (row-major M x 2048) for the final GEMM
  const int bb = bh >> 4, hh = bh & 15;
  float val = acc * rz;
  unsigned short h, l;
  split_hl(val, &h, &l);
  const size_t arow = (size_t)(bb * SEQ + i) * 2048;
  aohl[arow + hh * 64 + lane] = h;
  aohl[arow + 1024 + hh * 64 + lane] = l;
}

// ---------------------------------------------------------------------------
extern "C" void kernel_launch(void* const* d_in, const int* in_sizes, int n_in,
                              void* d_out, int out_size, void* d_ws, size_t ws_size,
                              hipStream_t stream)
{
  const float* query = (const float*)d_in[0];
  const float* key   = (const float*)d_in[1];
  const float* value = (const float*)d_in[2];
  const float* Wq    = (const float*)d_in[3];
  const float* bq    = (const float*)d_in[4];
  const float* Wk    = (const float*)d_in[5];
  const float* bk    = (const float*)d_in[6];
  const float* Wv    = (const float*)d_in[7];
  const float* bv    = (const float*)d_in[8];
  const float* Wo    = (const float*)d_in[9];
  const float* bo    = (const float*)d_in[10];

  // ws (54.5 MB): xhl(16) | whl(4) | qhl(16) | khl(16). V fp32 lives in d_out
  // (scratch until the final GEMM overwrites it).
  unsigned short* xhl = (unsigned short*)d_ws;            // 4096 x 2048
  unsigned short* whl = xhl + (size_t)4096 * 2048;        // 1024 x 2048
  unsigned short* qhl = whl + (size_t)1024 * 2048;        // 65536 x 128 (bhsd hl)
  unsigned short* khl = qhl + (size_t)65536 * 128;
  float* vpf = (float*)d_out;                             // 65536 x 64 fp32 (bhsd)

  hipLaunchKernelGGL(conv_xhl, dim3(4096), dim3(256), 0, stream, query, xhl);
  hipLaunchKernelGGL(conv_whl, dim3(1024), dim3(256), 0, stream, Wq, whl);
  hipLaunchKernelGGL(gemm_mfma, dim3(512), dim3(256), 0, stream, xhl, whl, bq,
                     (float*)nullptr, qhl, (float*)nullptr, 1);
  hipLaunchKernelGGL(conv_xhl, dim3(4096), dim3(256), 0, stream, key, xhl);
  hipLaunchKernelGGL(conv_whl, dim3(1024), dim3(256), 0, stream, Wk, whl);
  hipLaunchKernelGGL(gemm_mfma, dim3(512), dim3(256), 0, stream, xhl, whl, bk,
                     (float*)nullptr, khl, (float*)nullptr, 1);
  hipLaunchKernelGGL(conv_xhl, dim3(4096), dim3(256), 0, stream, value, xhl);
  hipLaunchKernelGGL(conv_whl, dim3(1024), dim3(256), 0, stream, Wv, whl);
  hipLaunchKernelGGL(gemm_mfma, dim3(512), dim3(256), 0, stream, xhl, whl, bv,
                     (float*)nullptr, (unsigned short*)nullptr, vpf, 2);
  hipLaunchKernelGGL(attn_topk, dim3(8192), dim3(512), 0, stream, qhl, khl, vpf, xhl);
  hipLaunchKernelGGL(conv_whl, dim3(1024), dim3(256), 0, stream, Wo, whl);
  hipLaunchKernelGGL(gemm_mfma, dim3(512), dim3(256), 0, stream, xhl, whl, bo,
                     (float*)d_out, (unsigned short*)nullptr, (float*)nullptr, 0);
}